// Round 11
// baseline (71.227 us; speedup 1.0000x reference)
//
#include <hip/hip_runtime.h>

// GlobalAttention: out = softmax_j(scores) @ H
// scores[i,j] = sum_m lrelu(Wh1[i,m]+Wh2[j,m]) * a[m]
// lrelu(t) = 0.6t + 0.4|t|; row-constant part drops in softmax:
// scores'[i,j] = s2[j] + sum_m b[m]*|Wh1[i,m]+Wh2[j,m]|, b = 0.4a.
//
// R11 = R10 + score R4C4 @ 128-thread blocks (2 blocks/CU preserved),
// bglob via scalar(SMEM) loads instead of LDS bsh, single-barrier dbuf,
// PV R8xC8 full-c. LDS strides 68/260 fl (odd # of 16B quads).

#define HALF 524288

#define FENCE_BAR() do {                                   \
    __builtin_amdgcn_sched_barrier(0);                     \
    asm volatile("s_waitcnt lgkmcnt(0)" ::: "memory");     \
    __builtin_amdgcn_s_barrier();                          \
    __builtin_amdgcn_sched_barrier(0);                     \
} while (0)

__device__ __forceinline__ void f4fma(float4& acc, float s, float4 h) {
    acc.x = fmaf(s, h.x, acc.x);
    acc.y = fmaf(s, h.y, acc.y);
    acc.z = fmaf(s, h.z, acc.z);
    acc.w = fmaf(s, h.w, acc.w);
}

// ---------- K1: Whp[z][i][m] = sum_{k in half z} H[i][k]*Wre[m][k]
// (unchanged from R10 — proven ~7.7us)
__global__ __launch_bounds__(256) void k1_gemm_wh(const float* __restrict__ H,
                                                  const float* __restrict__ W,
                                                  float* __restrict__ Whp) {
    __shared__ float As[64][36];
    __shared__ float Bs[32][36];
    const int bi = blockIdx.x, bm = blockIdx.y, bz = blockIdx.z;
    const int t = threadIdx.x;
    const int ti = t >> 4, tj = t & 15;
    const int i0 = ti * 4;
    const int half = bm >> 3;
    const int kbase = bz * 128;
    float acc[4][2] = {};
    for (int kc = 0; kc < 128; kc += 32) {
        const int kg = kbase + kc;
        {
            const int r = t >> 2, c = (t & 3) * 8;
            *(float4*)&As[r][c] = *(const float4*)&H[(bi * 64 + r) * 256 + kg + c];
            *(float4*)&As[r][c + 4] =
                *(const float4*)&H[(bi * 64 + r) * 256 + kg + c + 4];
        }
        {
            const int r = t >> 3, c = (t & 7) * 4;
            const int wrow = (bm * 32 + r) & 255;
            *(float4*)&Bs[r][c] =
                *(const float4*)&W[wrow * 512 + half * 256 + kg + c];
        }
        __syncthreads();
#pragma unroll
        for (int k = 0; k < 32; k += 4) {
            float4 a[4], b[2];
#pragma unroll
            for (int r = 0; r < 4; ++r) a[r] = *(const float4*)&As[i0 + r][k];
#pragma unroll
            for (int c = 0; c < 2; ++c) b[c] = *(const float4*)&Bs[tj + 16 * c][k];
#pragma unroll
            for (int r = 0; r < 4; ++r)
#pragma unroll
                for (int c = 0; c < 2; ++c) {
                    acc[r][c] = fmaf(a[r].x, b[c].x, acc[r][c]);
                    acc[r][c] = fmaf(a[r].y, b[c].y, acc[r][c]);
                    acc[r][c] = fmaf(a[r].z, b[c].z, acc[r][c]);
                    acc[r][c] = fmaf(a[r].w, b[c].w, acc[r][c]);
                }
        }
        __syncthreads();
    }
    float* dst = Whp + (size_t)bz * HALF;
#pragma unroll
    for (int r = 0; r < 4; ++r)
#pragma unroll
        for (int c = 0; c < 2; ++c)
            dst[(size_t)(bi * 64 + i0 + r) * 512 + bm * 32 + tj + 16 * c] = acc[r][c];
}

// ---------- kW: Wh = Whp0+Whp1, s2[j] = 0.6*sum a[m]*Wh2[j][m], bglob = 0.4a.
__global__ __launch_bounds__(256) void kW_merge(const float* __restrict__ Whp,
                                                const float* __restrict__ a,
                                                float* __restrict__ Wh,
                                                float* __restrict__ s2,
                                                float* __restrict__ bglob) {
    const int t = threadIdx.x;
    const int row = blockIdx.x * 2 + (t >> 7);
    const int col = (t & 127) * 4;
    const size_t off = (size_t)row * 512 + col;
    float4 v0 = *(const float4*)&Whp[off];
    float4 v1 = *(const float4*)&Whp[HALF + off];
    float4 v = make_float4(v0.x + v1.x, v0.y + v1.y, v0.z + v1.z, v0.w + v1.w);
    *(float4*)&Wh[off] = v;
    if (col >= 256) {
        float4 av = *(const float4*)&a[col - 256];
        float p = av.x * v.x + av.y * v.y + av.z * v.z + av.w * v.w;
#pragma unroll
        for (int o = 32; o > 0; o >>= 1) p += __shfl_xor(p, o);
        if ((t & 63) == 0) s2[row] = 0.6f * p;
    }
    if (blockIdx.x == 0 && t < 64) {
        float4 av = *(const float4*)&a[t * 4];
        *(float4*)&bglob[t * 4] =
            make_float4(0.4f * av.x, 0.4f * av.y, 0.4f * av.z, 0.4f * av.w);
    }
}

// ---------- KF: flash block = 32 i x 64 j, 128 threads, R4C4 score, R8C8 PV.
// Grid (32,16) = 512 blocks -> 2 blocks/CU (73.5 KB LDS each).
__global__ __launch_bounds__(128) void kF_flash(const float* __restrict__ Wh,
                                                const float* __restrict__ bglob,
                                                const float* __restrict__ s2,
                                                const float* __restrict__ H,
                                                float* __restrict__ avp,
                                                float* __restrict__ mbuf,
                                                float* __restrict__ lbuf) {
    __shared__ float SH[16640];  // score: X1[2][32][68]+X2[2][64][68]; PV: Hs[64][260]
    __shared__ float P[2176];    // 32 x 68
    float* X1 = SH;
    float* X2 = SH + 4352;
    float* Hs = SH;
    const int bi = blockIdx.x, bj = blockIdx.y;
    const int t = threadIdx.x;
    const int ti = t >> 4, tj = t & 15;  // ti 0..7, tj 0..15
    const int i0 = ti * 4;
    // score staging: X1 32x64 (4 f4/thr), X2 64x64 (8 f4/thr)
    const int r1 = t >> 2, c1 = (t & 3) * 16;
    const int r2 = t >> 1, c2 = (t & 1) * 32;
    const float* g1 = Wh + (size_t)(bi * 32 + r1) * 512 + c1;
    const float* g2 = Wh + (size_t)(bj * 64 + r2) * 512 + 256 + c2;
    // PV H staging: 64x256, 32 f4/thr (wave0 cols 0..127, wave1 128..255)
    const int hr = t & 63, hcb = (t >> 6) * 128;
    const float* gH = H + (size_t)(bj * 64 + hr) * 256 + hcb;

    float4 A[12], B[12];

#define LOADC(R, mc) do {                                       \
    R[0] = *(const float4*)(g1 + (mc) * 64);                    \
    R[1] = *(const float4*)(g1 + (mc) * 64 + 4);                \
    R[2] = *(const float4*)(g1 + (mc) * 64 + 8);                \
    R[3] = *(const float4*)(g1 + (mc) * 64 + 12);               \
    R[4] = *(const float4*)(g2 + (mc) * 64);                    \
    R[5] = *(const float4*)(g2 + (mc) * 64 + 4);                \
    R[6] = *(const float4*)(g2 + (mc) * 64 + 8);                \
    R[7] = *(const float4*)(g2 + (mc) * 64 + 12);               \
    R[8] = *(const float4*)(g2 + (mc) * 64 + 16);               \
    R[9] = *(const float4*)(g2 + (mc) * 64 + 20);               \
    R[10] = *(const float4*)(g2 + (mc) * 64 + 24);              \
    R[11] = *(const float4*)(g2 + (mc) * 64 + 28); } while (0)
#define WRITEC(R, buf) do {                                     \
    *(float4*)&X1[((buf) * 32 + r1) * 68 + c1] = R[0];          \
    *(float4*)&X1[((buf) * 32 + r1) * 68 + c1 + 4] = R[1];      \
    *(float4*)&X1[((buf) * 32 + r1) * 68 + c1 + 8] = R[2];      \
    *(float4*)&X1[((buf) * 32 + r1) * 68 + c1 + 12] = R[3];     \
    *(float4*)&X2[((buf) * 64 + r2) * 68 + c2] = R[4];          \
    *(float4*)&X2[((buf) * 64 + r2) * 68 + c2 + 4] = R[5];      \
    *(float4*)&X2[((buf) * 64 + r2) * 68 + c2 + 8] = R[6];      \
    *(float4*)&X2[((buf) * 64 + r2) * 68 + c2 + 12] = R[7];     \
    *(float4*)&X2[((buf) * 64 + r2) * 68 + c2 + 16] = R[8];     \
    *(float4*)&X2[((buf) * 64 + r2) * 68 + c2 + 20] = R[9];     \
    *(float4*)&X2[((buf) * 64 + r2) * 68 + c2 + 24] = R[10];    \
    *(float4*)&X2[((buf) * 64 + r2) * 68 + c2 + 28] = R[11]; } while (0)

    // prologue
    LOADC(A, 0);
    LOADC(B, 1);
    float s2v0 = s2[bj * 64 + tj];
    float s2v1 = s2[bj * 64 + tj + 16];
    float s2v2 = s2[bj * 64 + tj + 32];
    float s2v3 = s2[bj * 64 + tj + 48];
    WRITEC(A, 0);   // waits only A's loads (counted vmcnt)
    FENCE_BAR();

    float acc[4][4] = {};
#pragma unroll
    for (int mc = 0; mc < 4; ++mc) {
        const int buf = mc & 1;
        if (mc == 0) { WRITEC(B, 1); LOADC(A, 2); }
        else if (mc == 1) { WRITEC(A, 0); LOADC(B, 3); }
        else if (mc == 2) { WRITEC(B, 1); }
#pragma unroll
        for (int k = 0; k < 64; k += 4) {
            float4 x1[4], x2[4];
#pragma unroll
            for (int r = 0; r < 4; ++r)
                x1[r] = *(const float4*)&X1[(buf * 32 + i0 + r) * 68 + k];
#pragma unroll
            for (int c = 0; c < 4; ++c)
                x2[c] = *(const float4*)&X2[(buf * 64 + tj + 16 * c) * 68 + k];
            const float4 bv = *(const float4*)(bglob + mc * 64 + k);  // SMEM
#pragma unroll
            for (int r = 0; r < 4; ++r)
#pragma unroll
                for (int c = 0; c < 4; ++c) {
                    acc[r][c] = fmaf(fabsf(x1[r].x + x2[c].x), bv.x, acc[r][c]);
                    acc[r][c] = fmaf(fabsf(x1[r].y + x2[c].y), bv.y, acc[r][c]);
                    acc[r][c] = fmaf(fabsf(x1[r].z + x2[c].z), bv.z, acc[r][c]);
                    acc[r][c] = fmaf(fabsf(x1[r].w + x2[c].w), bv.w, acc[r][c]);
                }
        }
        FENCE_BAR();
    }

    // add s2
#pragma unroll
    for (int r = 0; r < 4; ++r) {
        acc[r][0] += s2v0; acc[r][1] += s2v1;
        acc[r][2] += s2v2; acc[r][3] += s2v3;
    }

    // issue all PV H loads now (32 f4); latency hides under softmax
    float4 h[32];
#pragma unroll
    for (int q = 0; q < 32; ++q) h[q] = *(const float4*)(gH + q * 4);

    // local softmax over the 64-j chunk (reduce across 16 tj lanes)
    float mmv[4], llv[4];
#pragma unroll
    for (int r = 0; r < 4; ++r) {
        float mm = fmaxf(fmaxf(acc[r][0], acc[r][1]), fmaxf(acc[r][2], acc[r][3]));
        mm = fmaxf(mm, __shfl_xor(mm, 1));
        mm = fmaxf(mm, __shfl_xor(mm, 2));
        mm = fmaxf(mm, __shfl_xor(mm, 4));
        mm = fmaxf(mm, __shfl_xor(mm, 8));
        float l0 = 0.f;
#pragma unroll
        for (int c = 0; c < 4; ++c) {
            acc[r][c] = __expf(acc[r][c] - mm);
            l0 += acc[r][c];
        }
        l0 += __shfl_xor(l0, 1);
        l0 += __shfl_xor(l0, 2);
        l0 += __shfl_xor(l0, 4);
        l0 += __shfl_xor(l0, 8);
#pragma unroll
        for (int c = 0; c < 4; ++c) P[(i0 + r) * 68 + tj + 16 * c] = acc[r][c];
        mmv[r] = mm; llv[r] = l0;
    }
    FENCE_BAR();  // P visible; score region (SH) dead -> reusable as Hs

    // stage Hs 64x256 (stride 260)
#pragma unroll
    for (int q = 0; q < 32; ++q) *(float4*)&Hs[hr * 260 + hcb + q * 4] = h[q];
    FENCE_BAR();  // Hs visible

    // PV: jj-outer, R8 x C8 (ca, cb), P reads broadcast.
    const int ti2 = t >> 5, tj2 = t & 31;
    const int ip = ti2 * 8;
    const int ca = tj2 * 4, cb = 128 + tj2 * 4;
    float4 acc2[8][2] = {};
#pragma unroll
    for (int jj = 0; jj < 64; jj += 4) {
        float4 pv[8];
#pragma unroll
        for (int r = 0; r < 8; ++r) pv[r] = *(const float4*)&P[(ip + r) * 68 + jj];
#pragma unroll
        for (int q = 0; q < 4; ++q) {
            float4 ha = *(const float4*)&Hs[(jj + q) * 260 + ca];
            float4 hb = *(const float4*)&Hs[(jj + q) * 260 + cb];
#pragma unroll
            for (int r = 0; r < 8; ++r) {
                const float s = (q == 0) ? pv[r].x : (q == 1) ? pv[r].y
                              : (q == 2) ? pv[r].z : pv[r].w;
                f4fma(acc2[r][0], s, ha);
                f4fma(acc2[r][1], s, hb);
            }
        }
    }
#pragma unroll
    for (int r = 0; r < 8; ++r) {
        const size_t o = (size_t)bj * 262144 + (size_t)(bi * 32 + ip + r) * 256;
        *(float4*)&avp[o + ca] = acc2[r][0];
        *(float4*)&avp[o + cb] = acc2[r][1];
    }
    if (tj == 0) {
        const int gi = bi * 32 + i0;
#pragma unroll
        for (int r = 0; r < 4; ++r) {
            mbuf[bj * 1024 + gi + r] = mmv[r];
            lbuf[bj * 1024 + gi + r] = llv[r];
        }
    }
#undef LOADC
#undef WRITEC
}

// ---------- KM: merge 16 j-chunks with flash rescaling.
__global__ __launch_bounds__(256) void kM_merge(const float* __restrict__ avp,
                                                const float* __restrict__ mbuf,
                                                const float* __restrict__ lbuf,
                                                float* __restrict__ out) {
    const int t = threadIdx.x;
    const int i = blockIdx.x * 4 + (t >> 6);
    const int c0 = (t & 63) * 4;
    float ms[16], es[16];
    float M = -1e30f;
#pragma unroll
    for (int s = 0; s < 16; ++s) {
        ms[s] = mbuf[s * 1024 + i];
        M = fmaxf(M, ms[s]);
    }
    float L = 0.f;
#pragma unroll
    for (int s = 0; s < 16; ++s) {
        es[s] = __expf(ms[s] - M);
        L = fmaf(es[s], lbuf[s * 1024 + i], L);
    }
    const float inv = 1.0f / L;
    float4 o = make_float4(0.f, 0.f, 0.f, 0.f);
#pragma unroll
    for (int s = 0; s < 16; ++s) {
        float4 p = *(const float4*)&avp[(size_t)s * 262144 + (size_t)i * 256 + c0];
        o.x = fmaf(es[s], p.x, o.x);
        o.y = fmaf(es[s], p.y, o.y);
        o.z = fmaf(es[s], p.z, o.z);
        o.w = fmaf(es[s], p.w, o.w);
    }
    o.x *= inv; o.y *= inv; o.z *= inv; o.w *= inv;
    *(float4*)&out[(size_t)i * 256 + c0] = o;
}

extern "C" void kernel_launch(void* const* d_in, const int* in_sizes, int n_in,
                              void* d_out, int out_size, void* d_ws, size_t ws_size,
                              hipStream_t stream) {
    const float* H = (const float*)d_in[0];
    const float* W = (const float*)d_in[1];
    const float* a = (const float*)d_in[2];
    float* out = (float*)d_out;
    float* ws = (float*)d_ws;

    // avp (4M floats) aliases Whp (1M floats): Whp dead after kW_merge.
    float* avp = ws;                     // 16 MB
    float* Whp = ws;                     // 4 MB (k1 out, kW in)
    float* Wh = ws + (4u << 20);         // 2 MB merged
    float* mbuf = Wh + HALF;             // 16K floats
    float* lbuf = mbuf + 16384;          // 16K floats
    float* s2 = lbuf + 16384;            // 1K floats
    float* bglob = s2 + 1024;            // 256 floats

    hipLaunchKernelGGL(k1_gemm_wh, dim3(16, 16, 2), dim3(256), 0, stream, H, W, Whp);
    hipLaunchKernelGGL(kW_merge, dim3(512), dim3(256), 0, stream, Whp, a, Wh, s2, bglob);
    hipLaunchKernelGGL(kF_flash, dim3(32, 16), dim3(128), 0, stream, Wh, bglob, s2, H,
                       avp, mbuf, lbuf);
    hipLaunchKernelGGL(kM_merge, dim3(256), dim3(256), 0, stream, avp, mbuf, lbuf, out);
}